// Round 3
// baseline (1435.914 us; speedup 1.0000x reference)
//
#include <hip/hip_runtime.h>

#define N_WORDS 262144
#define N_TAGS  512
#define BDIM    768
#define MDIM    128

typedef __attribute__((ext_vector_type(8))) short  bf16x8;
typedef __attribute__((ext_vector_type(4))) float  f32x4;
typedef __attribute__((ext_vector_type(4))) int    i32x4;

union FragU { i32x4 i; bf16x8 h; };

// RNE fp32 -> bf16 (inputs finite)
__device__ inline unsigned bf16_1(float a) {
    union { float f; unsigned u; } ua; ua.f = a;
    unsigned x = ua.u;
    x += 0x7fffu + ((x >> 16) & 1u);
    return x >> 16;
}
// pack two fp32 -> (bf16(b)<<16)|bf16(a)
__device__ inline unsigned bf16_2(float a, float b) {
    union { float f; unsigned u; } ua, ub; ua.f = a; ub.f = b;
    unsigned x = ua.u, y = ub.u;
    x += 0x7fffu + ((x >> 16) & 1u);
    y += 0x7fffu + ((y >> 16) & 1u);
    return (x >> 16) | (y & 0xffff0000u);
}

// ---------------------------------------------------------------------------
// tags: Tbf[t][m ^ ((t&7)<<3)] = bf16(2*tags_m[t][m])   (pre-swizzled rows so
// dist_kernel's linear LDS staging + XOR'd ds_read_b128 is conflict-spread)
// tsq[t] = sum_m tags_m^2 (fp32)
// ---------------------------------------------------------------------------
__global__ __launch_bounds__(128) void tags_kernel(
    const float* __restrict__ tags_embed, const float* __restrict__ tags_W,
    const float* __restrict__ tags_b, unsigned short* __restrict__ Tbf,
    float* __restrict__ tsq)
{
    __shared__ __align__(16) float sE[BDIM];
    __shared__ float red[128];
    const int t = blockIdx.x;
    const int m = threadIdx.x;

    for (int i = m; i < BDIM; i += 128) sE[i] = tags_embed[(size_t)t * BDIM + i];
    __syncthreads();

    float acc = tags_b[m];
    const float* Wr = tags_W + (size_t)m * BDIM;
    #pragma unroll 8
    for (int b = 0; b < BDIM; b += 4) {
        float4 w4 = *reinterpret_cast<const float4*>(Wr + b);
        float4 e4 = *reinterpret_cast<const float4*>(&sE[b]);
        acc += w4.x * e4.x + w4.y * e4.y + w4.z * e4.z + w4.w * e4.w;
    }
    Tbf[(size_t)t * MDIM + (m ^ ((t & 7) << 3))] = (unsigned short)bf16_1(2.0f * acc);

    red[m] = acc * acc;
    __syncthreads();
    for (int s = 64; s > 0; s >>= 1) {
        if (m < s) red[m] += red[m + s];
        __syncthreads();
    }
    if (m == 0) tsq[t] = red[0];
}

// words_W fp32 [128][768] -> bf16 (RNE), packed pairs (linear layout)
__global__ __launch_bounds__(256) void wconv_kernel(
    const float* __restrict__ W, unsigned* __restrict__ Wbf)
{
    int i = blockIdx.x * 256 + threadIdx.x;          // 49152 u32 pairs
    float2 f = reinterpret_cast<const float2*>(W)[i];
    Wbf[i] = bf16_2(f.x, f.y);
}

// ---------------------------------------------------------------------------
// proj: GEMM1 (transposed) + shuffle transpose -> wsm[word][m] bf16
// per wave 16 words; no LDS, no barriers. High occupancy HBM streamer.
// ---------------------------------------------------------------------------
__global__ __launch_bounds__(256, 4) void proj_kernel(
    const float* __restrict__ embed,                 // [N][768] fp32
    const unsigned short* __restrict__ Wbf,          // [128][768] bf16
    const float* __restrict__ bias,                  // [128] fp32
    unsigned short* __restrict__ wsm)                // [N][128] bf16 out
{
    const int lane = threadIdx.x & 63;
    const int wv   = threadIdx.x >> 6;
    const int w    = lane & 15;          // word within wave's 16
    const int q    = lane >> 4;          // k-group 0..3
    const int word0 = blockIdx.x * 64 + wv * 16;

    // GEMM1: C1T[m=128][word=16] = W . E^T
    f32x4 acc1[8];
    #pragma unroll
    for (int mt = 0; mt < 8; ++mt) acc1[mt] = (f32x4){0.f, 0.f, 0.f, 0.f};

    const float* erow = embed + (size_t)(word0 + w) * BDIM + q * 8;
    #pragma unroll
    for (int ks = 0; ks < 24; ++ks) {
        f32x4 e0 = *reinterpret_cast<const f32x4*>(erow + ks * 32);
        f32x4 e1 = *reinterpret_cast<const f32x4*>(erow + ks * 32 + 4);
        FragU bu;
        bu.i = (i32x4){ (int)bf16_2(e0.x, e0.y), (int)bf16_2(e0.z, e0.w),
                        (int)bf16_2(e1.x, e1.y), (int)bf16_2(e1.z, e1.w) };
        #pragma unroll
        for (int mt = 0; mt < 8; ++mt) {
            bf16x8 af = *reinterpret_cast<const bf16x8*>(
                Wbf + (size_t)(mt * 16 + w) * BDIM + ks * 32 + q * 8);
            acc1[mt] = __builtin_amdgcn_mfma_f32_16x16x32_bf16(af, bu.h, acc1[mt], 0, 0, 0);
        }
    }

    // bias + pack: lane (w,q) holds m = mt*16 + q*4 + r
    unsigned pk[8][2];
    #pragma unroll
    for (int mt = 0; mt < 8; ++mt) {
        f32x4 b4 = *reinterpret_cast<const f32x4*>(bias + mt * 16 + q * 4);
        f32x4 v  = acc1[mt] + b4;
        pk[mt][0] = bf16_2(v.x, v.y);
        pk[mt][1] = bf16_2(v.z, v.w);
    }

    // shuffle transpose: lane (w,q) collects Wm[w][ks*32 + q*8 + e], e=0..7
    const int src0 = w + 16 * ((2 * q) & 3);
    const int src1 = w + 16 * ((2 * q + 1) & 3);
    const int hi   = q >> 1;
    unsigned short* wrow = wsm + (size_t)(word0 + w) * MDIM;
    #pragma unroll
    for (int ks = 0; ks < 4; ++ks) {
        unsigned a0 = __shfl(pk[2 * ks][0],     src0, 64);
        unsigned a1 = __shfl(pk[2 * ks][1],     src0, 64);
        unsigned a2 = __shfl(pk[2 * ks][0],     src1, 64);
        unsigned a3 = __shfl(pk[2 * ks][1],     src1, 64);
        unsigned b0 = __shfl(pk[2 * ks + 1][0], src0, 64);
        unsigned b1 = __shfl(pk[2 * ks + 1][1], src0, 64);
        unsigned b2 = __shfl(pk[2 * ks + 1][0], src1, 64);
        unsigned b3 = __shfl(pk[2 * ks + 1][1], src1, 64);
        i32x4 st = (i32x4){ (int)(hi ? b0 : a0), (int)(hi ? b1 : a1),
                            (int)(hi ? b2 : a2), (int)(hi ? b3 : a3) };
        *reinterpret_cast<i32x4*>(wrow + ks * 32 + q * 8) = st;   // coalesced 16B
    }
}

// ---------------------------------------------------------------------------
// dist: GEMM2 + softmax. 256 blocks (1/CU), 8 waves; Tbf LDS-resident.
// Each wave: 16 words x 512 tags per iteration, 8 iterations (grid-strided).
// ---------------------------------------------------------------------------
__global__ __launch_bounds__(512, 1) void dist_kernel(
    const unsigned short* __restrict__ wsm,          // [N][128] bf16
    const unsigned short* __restrict__ Tbf,          // [512][128] bf16 swizzled
    const float* __restrict__ tsq,                   // [512] fp32
    float* __restrict__ out_logp, float* __restrict__ out_p)
{
    __shared__ __align__(16) unsigned short sT[N_TAGS * MDIM];   // 128 KB
    __shared__ __align__(16) float stsq[N_TAGS];                 // 2 KB

    const int tid  = threadIdx.x;
    const int lane = tid & 63;
    const int wv   = tid >> 6;
    const int w16  = lane & 15;
    const int q    = lane >> 4;

    // stage Tbf linearly (global already row-swizzled), coalesced 16B copies
    #pragma unroll
    for (int i = 0; i < 16; ++i) {
        int idx = (i * 512 + tid) * 8;    // ushort index
        *reinterpret_cast<i32x4*>(sT + idx) =
            *reinterpret_cast<const i32x4*>(Tbf + idx);
    }
    stsq[tid] = tsq[tid];
    __syncthreads();

    // per-lane swizzled A-frag byte offsets within a 4 KB tag-tile, per ks
    int aoff[4];
    #pragma unroll
    for (int ks = 0; ks < 4; ++ks)
        aoff[ks] = w16 * 256 + ((ks * 64 + q * 16) ^ ((w16 & 7) << 4));
    const char* aB = reinterpret_cast<const char*>(sT);

    int word0 = blockIdx.x * 1024 + wv * 16;

    // preload first B-frags (words_m for this wave's 16 words)
    FragU bf2[4];
    {
        const unsigned short* wr = wsm + (size_t)(word0 + w16) * MDIM;
        #pragma unroll
        for (int ks = 0; ks < 4; ++ks)
            bf2[ks].i = *reinterpret_cast<const i32x4*>(wr + ks * 32 + q * 8);
    }

    for (int it = 0; it < 8; ++it) {
        // software-pipeline next iteration's B-frags
        FragU nb[4];
        if (it < 7) {
            const unsigned short* wr = wsm + (size_t)(word0 + 128 + w16) * MDIM;
            #pragma unroll
            for (int ks = 0; ks < 4; ++ks)
                nb[ks].i = *reinterpret_cast<const i32x4*>(wr + ks * 32 + q * 8);
        }

        f32x4 acc2[32];
        #pragma unroll
        for (int tt = 0; tt < 32; ++tt) acc2[tt] = (f32x4){0.f, 0.f, 0.f, 0.f};

        #pragma unroll
        for (int tt = 0; tt < 32; ++tt) {
            #pragma unroll
            for (int ks = 0; ks < 4; ++ks) {
                bf16x8 af = *reinterpret_cast<const bf16x8*>(aB + tt * 4096 + aoff[ks]);
                acc2[tt] = __builtin_amdgcn_mfma_f32_16x16x32_bf16(af, bf2[ks].h, acc2[tt], 0, 0, 0);
            }
        }

        // x = 2*w.t - t^2 ; softmax over 512 tags (4 lanes share a word)
        float mx = -3.0e38f;
        #pragma unroll
        for (int tt = 0; tt < 32; ++tt) {
            f32x4 s4 = *reinterpret_cast<const f32x4*>(&stsq[tt * 16 + q * 4]);
            acc2[tt] -= s4;
            mx = fmaxf(mx, fmaxf(fmaxf(acc2[tt].x, acc2[tt].y),
                                 fmaxf(acc2[tt].z, acc2[tt].w)));
        }
        mx = fmaxf(mx, __shfl_xor(mx, 16, 64));
        mx = fmaxf(mx, __shfl_xor(mx, 32, 64));

        float s = 0.f;
        #pragma unroll
        for (int tt = 0; tt < 32; ++tt) {
            s += __expf(acc2[tt].x - mx);
            s += __expf(acc2[tt].y - mx);
            s += __expf(acc2[tt].z - mx);
            s += __expf(acc2[tt].w - mx);
        }
        s += __shfl_xor(s, 16, 64);
        s += __shfl_xor(s, 32, 64);

        const float neg = mx + __logf(s);

        const size_t row = (size_t)(word0 + w16) * N_TAGS;
        #pragma unroll
        for (int tt = 0; tt < 32; ++tt) {
            f32x4 lp, pp;
            lp.x = acc2[tt].x - neg;  pp.x = __expf(lp.x);
            lp.y = acc2[tt].y - neg;  pp.y = __expf(lp.y);
            lp.z = acc2[tt].z - neg;  pp.z = __expf(lp.z);
            lp.w = acc2[tt].w - neg;  pp.w = __expf(lp.w);
            *reinterpret_cast<f32x4*>(out_logp + row + tt * 16 + q * 4) = lp;
            *reinterpret_cast<f32x4*>(out_p    + row + tt * 16 + q * 4) = pp;
        }

        word0 += 128;
        #pragma unroll
        for (int ks = 0; ks < 4; ++ks) bf2[ks] = nb[ks];
    }
}

extern "C" void kernel_launch(void* const* d_in, const int* in_sizes, int n_in,
                              void* d_out, int out_size, void* d_ws, size_t ws_size,
                              hipStream_t stream) {
    const float* tags_embed  = (const float*)d_in[0];
    const float* words_embed = (const float*)d_in[1];
    const float* tags_W      = (const float*)d_in[2];
    const float* tags_b      = (const float*)d_in[3];
    const float* words_W     = (const float*)d_in[4];
    const float* words_b     = (const float*)d_in[5];

    float* out_logp = (float*)d_out;
    float* out_p    = out_logp + (size_t)N_WORDS * N_TAGS;

    // ws: Tbf [512][128] bf16 | tsq [512] f32 | Wbf [128][768] bf16 | wsm [N][128] bf16
    unsigned short* Tbf = (unsigned short*)d_ws;
    float*          tsq = (float*)(Tbf + (size_t)N_TAGS * MDIM);
    unsigned short* Wbf = (unsigned short*)(tsq + N_TAGS);
    unsigned short* wsm = Wbf + (size_t)MDIM * BDIM;

    tags_kernel<<<N_TAGS, 128, 0, stream>>>(tags_embed, tags_W, tags_b, Tbf, tsq);
    wconv_kernel<<<(MDIM * BDIM / 2) / 256, 256, 0, stream>>>(words_W, (unsigned*)Wbf);
    proj_kernel<<<N_WORDS / 64, 256, 0, stream>>>(words_embed, Wbf, words_b, wsm);
    dist_kernel<<<256, 512, 0, stream>>>(wsm, Tbf, tsq, out_logp, out_p);
}

// Round 4
// 871.816 us; speedup vs baseline: 1.6470x; 1.6470x over previous
//
#include <hip/hip_runtime.h>

#define N_WORDS 262144
#define N_TAGS  512
#define BDIM    768
#define MDIM    128

typedef __attribute__((ext_vector_type(8))) short  bf16x8;
typedef __attribute__((ext_vector_type(4))) float  f32x4;
typedef __attribute__((ext_vector_type(4))) int    i32x4;

union FragU { i32x4 i; bf16x8 h; };

// RNE fp32 -> bf16 (inputs finite)
__device__ inline unsigned bf16_1(float a) {
    union { float f; unsigned u; } ua; ua.f = a;
    unsigned x = ua.u;
    x += 0x7fffu + ((x >> 16) & 1u);
    return x >> 16;
}
// pack two fp32 -> (bf16(b)<<16)|bf16(a)
__device__ inline unsigned bf16_2(float a, float b) {
    union { float f; unsigned u; } ua, ub; ua.f = a; ub.f = b;
    unsigned x = ua.u, y = ub.u;
    x += 0x7fffu + ((x >> 16) & 1u);
    y += 0x7fffu + ((y >> 16) & 1u);
    return (x >> 16) | (y & 0xffff0000u);
}

// ---------------------------------------------------------------------------
// tags: Tbf[t][m] = bf16(2*tags_m[t][m])  (linear, k-contiguous A-frag layout)
//       tsq[t]    = sum_m tags_m^2 (fp32)
// ---------------------------------------------------------------------------
__global__ __launch_bounds__(128) void tags_kernel(
    const float* __restrict__ tags_embed, const float* __restrict__ tags_W,
    const float* __restrict__ tags_b, unsigned short* __restrict__ Tbf,
    float* __restrict__ tsq)
{
    __shared__ __align__(16) float sE[BDIM];
    __shared__ float red[128];
    const int t = blockIdx.x;
    const int m = threadIdx.x;

    for (int i = m; i < BDIM; i += 128) sE[i] = tags_embed[(size_t)t * BDIM + i];
    __syncthreads();

    float acc = tags_b[m];
    const float* Wr = tags_W + (size_t)m * BDIM;
    #pragma unroll 8
    for (int b = 0; b < BDIM; b += 4) {
        float4 w4 = *reinterpret_cast<const float4*>(Wr + b);
        float4 e4 = *reinterpret_cast<const float4*>(&sE[b]);
        acc += w4.x * e4.x + w4.y * e4.y + w4.z * e4.z + w4.w * e4.w;
    }
    Tbf[(size_t)t * MDIM + m] = (unsigned short)bf16_1(2.0f * acc);

    red[m] = acc * acc;
    __syncthreads();
    for (int s = 64; s > 0; s >>= 1) {
        if (m < s) red[m] += red[m + s];
        __syncthreads();
    }
    if (m == 0) tsq[t] = red[0];
}

// words_W fp32 [128][768] -> bf16 (RNE), packed pairs (linear layout)
__global__ __launch_bounds__(256) void wconv_kernel(
    const float* __restrict__ W, unsigned* __restrict__ Wbf)
{
    int i = blockIdx.x * 256 + threadIdx.x;          // 49152 u32 pairs
    float2 f = reinterpret_cast<const float2*>(W)[i];
    Wbf[i] = bf16_2(f.x, f.y);
}

// ---------------------------------------------------------------------------
// Fused words kernel: 256 threads = 4 waves, 16 words per block.
//  P0: stage embed -> LDS bf16 (convert once, XOR-swizzled bits[6:4])
//  P1: GEMM1 m-split: wave v -> m-tiles {2v,2v+1}, acc1[2]
//  P2: shuffle-transpose -> wave v holds B2-fragment ks=v slice -> LDS exchange
//  P3: GEMM2 tag-split: wave v -> tags v*128..+127, acc2[8]
//  P4: softmax with cross-wave (max,sum) combine via LDS
//  P5: epilogue stores
// ---------------------------------------------------------------------------
__global__ __launch_bounds__(256, 4) void words_kernel(
    const float* __restrict__ embed,                 // [N][768] fp32
    const unsigned short* __restrict__ Wbf,          // [128][768] bf16
    const float* __restrict__ bias,                  // [128] fp32
    const unsigned short* __restrict__ Tbf,          // [512][128] bf16 (2*tags_m)
    const float* __restrict__ tsq,                   // [512] fp32
    float* __restrict__ out_logp, float* __restrict__ out_p)
{
    __shared__ __align__(16) unsigned short sEb[16 * BDIM];  // 24 KB bf16, swizzled
    __shared__ __align__(16) int sBF[4][64][4];              // 4 KB frag exchange
    __shared__ float sMx[4][16];
    __shared__ float sSm[4][16];

    const int tid  = threadIdx.x;
    const int lane = tid & 63;
    const int v    = tid >> 6;       // wave 0..3
    const int w16  = lane & 15;      // word within block's 16
    const int q    = lane >> 4;      // k-group 0..3
    const int word0 = blockIdx.x * 16;

    // ---- P0: stage embed -> LDS (bf16, swizzled) ----
    {
        const int w = tid >> 4;      // 0..15 word
        const int s = tid & 15;      // segment
        const float* src = embed + (size_t)(word0 + w) * BDIM + s * 4;
        char* drow = reinterpret_cast<char*>(sEb) + w * 1536;
        #pragma unroll
        for (int r = 0; r < 12; ++r) {
            f32x4 e = *reinterpret_cast<const f32x4*>(src + r * 64);
            unsigned long long p8 =
                ((unsigned long long)bf16_2(e.z, e.w) << 32) | bf16_2(e.x, e.y);
            int byte = ((s + 16 * r) * 8) ^ ((w & 7) << 4);
            *reinterpret_cast<unsigned long long*>(drow + byte) = p8;
        }
    }
    __syncthreads();

    // ---- P1: GEMM1 m-split ----
    f32x4 acc1[2];
    acc1[0] = (f32x4){0.f, 0.f, 0.f, 0.f};
    acc1[1] = (f32x4){0.f, 0.f, 0.f, 0.f};
    {
        const char* eB = reinterpret_cast<const char*>(sEb) + w16 * 1536;
        const unsigned short* A0 = Wbf + (size_t)((2 * v)     * 16 + w16) * BDIM + q * 8;
        const unsigned short* A1 = Wbf + (size_t)((2 * v + 1) * 16 + w16) * BDIM + q * 8;
        #pragma unroll
        for (int ks = 0; ks < 24; ++ks) {
            bf16x8 bfrag = *reinterpret_cast<const bf16x8*>(
                eB + (((ks * 64 + q * 16) ^ ((w16 & 7) << 4))));
            bf16x8 a0 = *reinterpret_cast<const bf16x8*>(A0 + ks * 32);
            bf16x8 a1 = *reinterpret_cast<const bf16x8*>(A1 + ks * 32);
            acc1[0] = __builtin_amdgcn_mfma_f32_16x16x32_bf16(a0, bfrag, acc1[0], 0, 0, 0);
            acc1[1] = __builtin_amdgcn_mfma_f32_16x16x32_bf16(a1, bfrag, acc1[1], 0, 0, 0);
        }
    }

    // ---- P2: bias + pack + shuffle transpose -> ks=v slice -> LDS ----
    unsigned pk0[2], pk1[2];
    {
        f32x4 b4 = *reinterpret_cast<const f32x4*>(bias + (2 * v) * 16 + q * 4);
        f32x4 val = acc1[0] + b4;
        pk0[0] = bf16_2(val.x, val.y);
        pk0[1] = bf16_2(val.z, val.w);
        b4 = *reinterpret_cast<const f32x4*>(bias + (2 * v + 1) * 16 + q * 4);
        val = acc1[1] + b4;
        pk1[0] = bf16_2(val.x, val.y);
        pk1[1] = bf16_2(val.z, val.w);
    }
    {
        const int src0 = w16 + 16 * ((2 * q) & 3);
        const int src1 = w16 + 16 * ((2 * q + 1) & 3);
        const int hi   = q >> 1;
        unsigned a0 = __shfl(pk0[0], src0, 64);
        unsigned a1 = __shfl(pk0[1], src0, 64);
        unsigned a2 = __shfl(pk0[0], src1, 64);
        unsigned a3 = __shfl(pk0[1], src1, 64);
        unsigned b0 = __shfl(pk1[0], src0, 64);
        unsigned b1 = __shfl(pk1[1], src0, 64);
        unsigned b2 = __shfl(pk1[0], src1, 64);
        unsigned b3 = __shfl(pk1[1], src1, 64);
        i32x4 slice = (i32x4){ (int)(hi ? b0 : a0), (int)(hi ? b1 : a1),
                               (int)(hi ? b2 : a2), (int)(hi ? b3 : a3) };
        *reinterpret_cast<i32x4*>(&sBF[v][lane][0]) = slice;
    }
    __syncthreads();

    FragU bf2[4];
    #pragma unroll
    for (int ks = 0; ks < 4; ++ks)
        bf2[ks].i = *reinterpret_cast<const i32x4*>(&sBF[ks][lane][0]);

    // ---- P3: GEMM2 tag-split: wave v -> 128 tags ----
    f32x4 acc2[8];
    #pragma unroll
    for (int tt = 0; tt < 8; ++tt) acc2[tt] = (f32x4){0.f, 0.f, 0.f, 0.f};

    {
        const unsigned short* Ab = Tbf + (size_t)(v * 128 + w16) * MDIM + q * 8;
        #pragma unroll
        for (int tt = 0; tt < 8; ++tt) {
            #pragma unroll
            for (int ks = 0; ks < 4; ++ks) {
                bf16x8 af = *reinterpret_cast<const bf16x8*>(Ab + tt * 16 * MDIM + ks * 32);
                acc2[tt] = __builtin_amdgcn_mfma_f32_16x16x32_bf16(af, bf2[ks].h, acc2[tt], 0, 0, 0);
            }
        }
    }

    // ---- P4: x = 2wt - t^2, softmax with cross-wave combine ----
    float mx = -3.0e38f;
    #pragma unroll
    for (int tt = 0; tt < 8; ++tt) {
        f32x4 s4 = *reinterpret_cast<const f32x4*>(tsq + v * 128 + tt * 16 + q * 4);
        acc2[tt] -= s4;
        mx = fmaxf(mx, fmaxf(fmaxf(acc2[tt].x, acc2[tt].y),
                             fmaxf(acc2[tt].z, acc2[tt].w)));
    }
    mx = fmaxf(mx, __shfl_xor(mx, 16, 64));
    mx = fmaxf(mx, __shfl_xor(mx, 32, 64));

    float s = 0.f;
    #pragma unroll
    for (int tt = 0; tt < 8; ++tt) {
        s += __expf(acc2[tt].x - mx);
        s += __expf(acc2[tt].y - mx);
        s += __expf(acc2[tt].z - mx);
        s += __expf(acc2[tt].w - mx);
    }
    s += __shfl_xor(s, 16, 64);
    s += __shfl_xor(s, 32, 64);

    if (lane < 16) {
        sMx[v][lane] = mx;
        sSm[v][lane] = s;
    }
    __syncthreads();

    float M = sMx[0][w16];
    #pragma unroll
    for (int u = 1; u < 4; ++u) M = fmaxf(M, sMx[u][w16]);
    float S = 0.f;
    #pragma unroll
    for (int u = 0; u < 4; ++u) S += sSm[u][w16] * __expf(sMx[u][w16] - M);
    const float neg = M + __logf(S);

    // ---- P5: epilogue ----
    const size_t row = (size_t)(word0 + w16) * N_TAGS + v * 128;
    #pragma unroll
    for (int tt = 0; tt < 8; ++tt) {
        f32x4 lp, pp;
        lp.x = acc2[tt].x - neg;  pp.x = __expf(lp.x);
        lp.y = acc2[tt].y - neg;  pp.y = __expf(lp.y);
        lp.z = acc2[tt].z - neg;  pp.z = __expf(lp.z);
        lp.w = acc2[tt].w - neg;  pp.w = __expf(lp.w);
        *reinterpret_cast<f32x4*>(out_logp + row + tt * 16 + q * 4) = lp;
        *reinterpret_cast<f32x4*>(out_p    + row + tt * 16 + q * 4) = pp;
    }
}

extern "C" void kernel_launch(void* const* d_in, const int* in_sizes, int n_in,
                              void* d_out, int out_size, void* d_ws, size_t ws_size,
                              hipStream_t stream) {
    const float* tags_embed  = (const float*)d_in[0];
    const float* words_embed = (const float*)d_in[1];
    const float* tags_W      = (const float*)d_in[2];
    const float* tags_b      = (const float*)d_in[3];
    const float* words_W     = (const float*)d_in[4];
    const float* words_b     = (const float*)d_in[5];

    float* out_logp = (float*)d_out;
    float* out_p    = out_logp + (size_t)N_WORDS * N_TAGS;

    // ws: Tbf [512][128] bf16 | tsq [512] f32 | Wbf [128][768] bf16
    unsigned short* Tbf = (unsigned short*)d_ws;
    float*          tsq = (float*)(Tbf + (size_t)N_TAGS * MDIM);
    unsigned short* Wbf = (unsigned short*)(tsq + N_TAGS);

    tags_kernel<<<N_TAGS, 128, 0, stream>>>(tags_embed, tags_W, tags_b, Tbf, tsq);
    wconv_kernel<<<(MDIM * BDIM / 2) / 256, 256, 0, stream>>>(words_W, (unsigned*)Wbf);
    words_kernel<<<N_WORDS / 16, 256, 0, stream>>>(
        words_embed, Wbf, words_b, Tbf, tsq, out_logp, out_p);
}